// Round 10
// baseline (15.557 us; speedup 1.0000x reference)
//
#include <hip/hip_runtime.h>
#include <hip/hip_bf16.h>
#include <math.h>

#ifndef M_PI
#define M_PI 3.14159265358979323846
#endif

namespace mp {

constexpr int NK   = 1024;
constexpr int S    = 256;
constexpr int NREF = 4;
constexpr int BV   = 128;   // B * IT_M
constexpr int BIV  = 2048;  // BV * IT_R

// ---- wave-wide (64-lane) all-reduce sum ----
template <typename T>
__device__ inline T wsum(T v) {
#pragma unroll
  for (int mk = 32; mk >= 1; mk >>= 1) v += __shfl_xor(v, mk, 64);
  return v;
}

// ---- general 3x3 inverse (adjugate / det) in f64 (done once per wave),
//      result delivered as f32 rows for the f32 backproject ----
__device__ inline void inv3f(const float* __restrict__ K, float Kf[9]) {
  double a = K[0], b = K[1], c = K[2];
  double d = K[3], e = K[4], f = K[5];
  double g = K[6], h = K[7], i = K[8];
  double A  =  (e * i - f * h);
  double Bm = -(d * i - f * g);
  double C  =  (d * h - e * g);
  double det = a * A + b * Bm + c * C;
  double inv = 1.0 / det;
  Kf[0] = (float)(A * inv);  Kf[1] = (float)(-(b * i - c * h) * inv);  Kf[2] = (float)( (b * f - c * e) * inv);
  Kf[3] = (float)(Bm * inv); Kf[4] = (float)( (a * i - c * g) * inv);  Kf[5] = (float)(-(a * f - c * d) * inv);
  Kf[6] = (float)(C * inv);  Kf[7] = (float)(-(a * h - b * g) * inv);  Kf[8] = (float)( (a * e - b * d) * inv);
}

__device__ inline float det3f(float a, float b, float c,
                              float d, float e, float f,
                              float g, float h, float i) {
  return a * (e * i - f * h) - b * (d * i - f * g) + c * (d * h - e * g);
}

// ---- weighted Procrustes for one wave (4 points/lane, weights as a 4-bit
//      mask), fully f32. Horn/Davenport quaternion via QUEST closed form
//      (char poly + Newton-from-above + adjugate eigenvector). All lanes
//      hold identical reduced values -> branches wave-uniform. ----
__device__ inline void fitq(const float X[4][3], const float Y[4][3],
                            unsigned wm, float R[9], float t[3]) {
  // acc: [0]=sw, [1..3]=sx, [4..6]=sy, [7+3i+j]=Sxy[i][j]
  float acc[16];
  acc[0] = (float)__popc(wm);
#pragma unroll
  for (int r = 1; r < 16; ++r) acc[r] = 0.0f;
#pragma unroll
  for (int k = 0; k < 4; ++k) {
    bool w = (wm >> k) & 1u;
    float x0 = w ? X[k][0] : 0.0f, x1 = w ? X[k][1] : 0.0f, x2 = w ? X[k][2] : 0.0f;
    float y0 = Y[k][0], y1 = Y[k][1], y2 = Y[k][2];
    acc[1] += x0; acc[2] += x1; acc[3] += x2;
    acc[4] += w ? y0 : 0.0f; acc[5] += w ? y1 : 0.0f; acc[6] += w ? y2 : 0.0f;
    acc[7]  += x0 * y0; acc[8]  += x0 * y1; acc[9]  += x0 * y2;
    acc[10] += x1 * y0; acc[11] += x1 * y1; acc[12] += x1 * y2;
    acc[13] += x2 * y0; acc[14] += x2 * y1; acc[15] += x2 * y2;
  }
  // wave butterfly: 16 independent chains, 6 levels, single-b32 shuffles
#pragma unroll
  for (int mk = 32; mk >= 1; mk >>= 1)
#pragma unroll
    for (int r = 0; r < 16; ++r) acc[r] += __shfl_xor(acc[r], mk, 64);

  float sw = acc[0];
  float rinv = __fdividef(1.0f, sw + 1e-8f);  // reference's +1e-8 epsilon
  float cx[3], cy[3];
#pragma unroll
  for (int i = 0; i < 3; ++i) { cx[i] = acc[1 + i] * rinv; cy[i] = acc[4 + i] * rinv; }
  float H[3][3];
#pragma unroll
  for (int i = 0; i < 3; ++i)
#pragma unroll
    for (int j = 0; j < 3; ++j)
      H[i][j] = acc[7 + 3 * i + j] - cx[i] * acc[4 + j] - acc[1 + i] * cy[j] +
                sw * cx[i] * cy[j];

  // Horn's K (symmetric, traceless), q = (w,x,y,z)
  float k00 =  H[0][0] + H[1][1] + H[2][2];
  float k11 =  H[0][0] - H[1][1] - H[2][2];
  float k22 = -H[0][0] + H[1][1] - H[2][2];
  float k33 = -H[0][0] - H[1][1] + H[2][2];
  float k01 = H[1][2] - H[2][1];
  float k02 = H[2][0] - H[0][2];
  float k03 = H[0][1] - H[1][0];
  float k12 = H[0][1] + H[1][0];
  float k13 = H[0][2] + H[2][0];
  float k23 = H[1][2] + H[2][1];

  // char poly p(l) = l^4 + e2 l^2 - e3 l + e4 (trace = 0)
  float e2 = (k00 * k11 - k01 * k01) + (k00 * k22 - k02 * k02) +
             (k00 * k33 - k03 * k03) + (k11 * k22 - k12 * k12) +
             (k11 * k33 - k13 * k13) + (k22 * k33 - k23 * k23);
  float e3 = det3f(k00, k01, k02, k01, k11, k12, k02, k12, k22) +
             det3f(k00, k01, k03, k01, k11, k13, k03, k13, k33) +
             det3f(k00, k02, k03, k02, k22, k23, k03, k23, k33) +
             det3f(k11, k12, k13, k12, k22, k23, k13, k23, k33);
  float M00 = det3f(k11, k12, k13, k12, k22, k23, k13, k23, k33);
  float M01 = det3f(k01, k12, k13, k02, k22, k23, k03, k23, k33);
  float M02 = det3f(k01, k11, k13, k02, k12, k23, k03, k13, k33);
  float M03 = det3f(k01, k11, k12, k02, k12, k22, k03, k13, k23);
  float e4 = k00 * M00 - k01 * M01 + k02 * M02 - k03 * M03;

  // upper bound: min(Gershgorin, Frobenius)*safety; ||K||F^2 = -2 e2.
  float g0 = k00 + fabsf(k01) + fabsf(k02) + fabsf(k03);
  float g1 = k11 + fabsf(k01) + fabsf(k12) + fabsf(k13);
  float g2 = k22 + fabsf(k02) + fabsf(k12) + fabsf(k23);
  float g3 = k33 + fabsf(k03) + fabsf(k13) + fabsf(k23);
  float gersh = fmaxf(fmaxf(g0, g1), fmaxf(g2, g3));
  float frob = sqrtf(fmaxf(-2.0f * e2, 0.0f));
  float lam = fmaxf(fminf(gersh, frob), 0.0f) * 1.00001f;

  // Newton from above, fast divide. Degenerate K~0: 0/0 -> NaN -> caught by
  // the n2 guard (R = I, matches SVD-of-zeros identity behavior).
#pragma unroll
  for (int i = 0; i < 9; ++i) {
    float l2 = lam * lam;
    float p  = ((l2 + e2) * lam - e3) * lam + e4;
    float pp = (4.0f * l2 + 2.0f * e2) * lam - e3;
    lam -= __fdividef(p, pp);
  }

  // eigenvector = max-|diagonal| column of adj(K - lam*I) (= kappa*q*q^T)
  float m00 = k00 - lam, m11 = k11 - lam, m22 = k22 - lam, m33 = k33 - lam;
  float c00 = det3f(m11, k12, k13, k12, m22, k23, k13, k23, m33);
  float c01 = -det3f(k01, k12, k13, k02, m22, k23, k03, k23, m33);
  float c02 = det3f(k01, m11, k13, k02, k12, k23, k03, k13, m33);
  float c03 = -det3f(k01, m11, k12, k02, k12, m22, k03, k13, k23);
  float c11 = det3f(m00, k02, k03, k02, m22, k23, k03, k23, m33);
  float c12 = -det3f(m00, k01, k03, k02, k12, k23, k03, k13, m33);
  float c13 = det3f(m00, k01, k02, k02, k12, m22, k03, k13, k23);
  float c22 = det3f(m00, k01, k03, k01, m11, k13, k03, k13, m33);
  float c23 = -det3f(m00, k01, k02, k01, m11, k12, k03, k13, k23);
  float c33 = det3f(m00, k01, k02, k01, m11, k12, k02, k12, m22);

  float a0 = fabsf(c00), a1 = fabsf(c11), a2 = fabsf(c22), a3 = fabsf(c33);
  float q0 = c00, q1 = c01, q2 = c02, q3 = c03, bb = a0;
  bool t1 = a1 > bb; bb = t1 ? a1 : bb;
  q0 = t1 ? c01 : q0; q1 = t1 ? c11 : q1; q2 = t1 ? c12 : q2; q3 = t1 ? c13 : q3;
  bool t2 = a2 > bb; bb = t2 ? a2 : bb;
  q0 = t2 ? c02 : q0; q1 = t2 ? c12 : q1; q2 = t2 ? c22 : q2; q3 = t2 ? c23 : q3;
  bool t3 = a3 > bb;
  q0 = t3 ? c03 : q0; q1 = t3 ? c13 : q1; q2 = t3 ? c23 : q2; q3 = t3 ? c33 : q3;

  float n2 = q0 * q0 + q1 * q1 + q2 * q2 + q3 * q3;
  bool ok = n2 > 1e-30f;  // degenerate -> R = I
  float qn = rsqrtf(ok ? n2 : 1.0f);
  float qw = ok ? q0 * qn : 1.0f;
  float qx = ok ? q1 * qn : 0.0f;
  float qy = ok ? q2 * qn : 0.0f;
  float qz = ok ? q3 * qn : 0.0f;

  R[0] = 1.0f - 2.0f * (qy * qy + qz * qz);
  R[1] = 2.0f * (qx * qy - qw * qz);
  R[2] = 2.0f * (qx * qz + qw * qy);
  R[3] = 2.0f * (qx * qy + qw * qz);
  R[4] = 1.0f - 2.0f * (qx * qx + qz * qz);
  R[5] = 2.0f * (qy * qz - qw * qx);
  R[6] = 2.0f * (qx * qz - qw * qy);
  R[7] = 2.0f * (qy * qz + qw * qx);
  R[8] = 1.0f - 2.0f * (qx * qx + qy * qy);
#pragma unroll
  for (int i = 0; i < 3; ++i)
    t[i] = cy[i] - (R[3 * i] * cx[0] + R[3 * i + 1] * cx[1] + R[3 * i + 2] * cx[2]);
}

// ---- fit kernel: 2048 blocks x 64 threads; ONE candidate per wave (4
// points/lane) -> 2 waves/SIMD for latency hiding (r9 post-mortem: at 1
// wave/SIMD the kernel was ~10x stall-bound; issue work is cheap now).
// Fully f32 pipeline; NO device-scope fences (r7 post-mortem).
// Exactness/drift model (same as r9, which passed absmax 0.0):
//  * final procrustes re-fits weights already fit in the loop -> saving the
//    fit at (it==0 || improved) reproduces it.
//  * early-exit on non-improving iteration is a fixed point of the loop.
//  * 'improved' = integer popcount vs pre=5; with random clouds refsum ~ 0,
//    flip probability << 1e-6; smooth outputs tolerate ~1e-5 R drift. ----
__global__ __launch_bounds__(64) void pose_fit_kernel(
    const float* __restrict__ kps0, const float* __restrict__ kps1,
    const float* __restrict__ depth0, const float* __restrict__ depth1,
    const float* __restrict__ T01,
    const float* __restrict__ K0, const float* __restrict__ K1,
    const int* __restrict__ sidx, const int* __restrict__ sransac,
    float* __restrict__ oscore, float* __restrict__ olr,
    float* __restrict__ olt) {
  const int m = blockIdx.x;      // candidate (0..2047)
  const int v = m >> 4;          // sample row (0..127), IT_R = 16
  const int b = v >> 4;          // batch (0..7), IT_M = 16
  const int lane = threadIdx.x;  // 0..63

  float Kf0[9], Kf1[9];
  inv3f(K0 + b * 9, Kf0);
  inv3f(K1 + b * 9, Kf1);

  // gather + backproject 4 points per lane (f32)
  float X[4][3], Y[4][3];
#pragma unroll
  for (int k = 0; k < 4; ++k) {
    int s = lane + 64 * k;
    int idx = sidx[v * S + s];
    int i0 = idx >> 10;       // idx / NK
    int i1 = idx & (NK - 1);  // idx % NK
    float u0 = kps0[b * 2 * NK + i0];
    float w0 = kps0[b * 2 * NK + NK + i0];
    float d0 = depth0[b * NK + i0];
    float u1 = kps1[b * 2 * NK + i1];
    float w1 = kps1[b * 2 * NK + NK + i1];
    float d1 = depth1[b * NK + i1];
#pragma unroll
    for (int i = 0; i < 3; ++i) {
      X[k][i] = d0 * (Kf0[3 * i] * u0 + Kf0[3 * i + 1] * w0 + Kf0[3 * i + 2]);
      Y[k][i] = d1 * (Kf1[3 * i] * u1 + Kf1[3 * i + 1] * w1 + Kf1[3 * i + 2]);
    }
  }

  // seed mask (bit k <=> point s = lane + 64k); set-semantics via OR
  unsigned wm = 0;
#pragma unroll
  for (int c = 0; c < 5; ++c) {
    int r = sransac[m * 5 + c];
    if ((r & 63) == lane) wm |= 1u << (r >> 6);
  }

  int pre = 5;  // NC (refsum/pre exact ints)
  float Rs[9], ts[3], sqs[4];  // saved state for the inl_final fit
  for (int it = 0; it < NREF; ++it) {
    float R[9], t[3];
    fitq(X, Y, wm, R, t);
    unsigned nwm = 0;
    float sq32[4];
#pragma unroll
    for (int k = 0; k < 4; ++k) {
      float e0 = Y[k][0] - (R[0] * X[k][0] + R[1] * X[k][1] + R[2] * X[k][2] + t[0]);
      float e1 = Y[k][1] - (R[3] * X[k][0] + R[4] * X[k][1] + R[5] * X[k][2] + t[1]);
      float e2 = Y[k][2] - (R[6] * X[k][0] + R[7] * X[k][1] + R[8] * X[k][2] + t[2]);
      float sq = e0 * e0 + e1 * e1 + e2 * e2;
      sq32[k] = sq;
      nwm |= (sq < 0.0225f) ? (1u << k) : 0u;  // (r < 0.15)
    }
    int rs = wsum(__popc(nwm));        // wave-uniform refsum
    bool imp = rs > pre;
    bool sv = (it == 0) || imp;        // this fit is (currently) the final one
#pragma unroll
    for (int i = 0; i < 9; ++i) Rs[i] = sv ? R[i] : Rs[i];
#pragma unroll
    for (int i = 0; i < 3; ++i) ts[i] = sv ? t[i] : ts[i];
#pragma unroll
    for (int k = 0; k < 4; ++k) sqs[k] = sv ? sq32[k] : sqs[k];
    pre = imp ? rs : pre;
    wm  = imp ? nwm : wm;
    if (!imp) break;  // exact fixed point of the reference loop
  }

  // smooth score from saved residuals
  float sc = 0.0f;
#pragma unroll
  for (int k = 0; k < 4; ++k) {
    float r = sqrtf(sqs[k]);
    float xar = 5.0f * (1.0f - r * (1.0f / 0.15f));  // BETA*(1-r/TH)
    sc += 1.0f / (1.0f + __expf(-xar));
  }
  sc = wsum(sc);

  // pose errors vs ground truth T_0to1[b] (tail identical to r8/r9)
  const float* Tb = T01 + b * 16;
  float tr = 0.0f;
#pragma unroll
  for (int i = 0; i < 3; ++i)
#pragma unroll
    for (int j = 0; j < 3; ++j) tr += Rs[i * 3 + j] * Tb[i * 4 + j];
  double xcl = 0.5 * ((double)tr - 1.0);
  const double lo = -1.0 + 1e-6, hi = 1.0 - 1e-6;
  xcl = xcl < lo ? lo : (xcl > hi ? hi : xcl);
  float rot_err = acosf((float)xcl) * (float)(180.0 / M_PI);
  float te0 = ts[0] - Tb[3];
  float te1 = ts[1] - Tb[7];
  float te2 = ts[2] - Tb[11];
  float terr = sqrtf(te0 * te0 + te1 * te1 + te2 * te2);
  float lr = 45.0f * tanhf(rot_err * (1.0f / 45.0f));  // MAX_ROT
  float lt = tanhf(terr);                              // MAX_TRANS = 1

  if (lane == 0) {
    oscore[m] = sc;
    olr[m] = lr;
    olt[m] = lt;
  }
}

// ---- softmax(score/TEMP) over IT_R=16, weighted losses, mean over IT_M=16 ----
// Output is FLOAT32, flat (2, B, 1) = [rot x8, trans x8].
__global__ __launch_bounds__(128) void pose_reduce_kernel(
    const float* __restrict__ oscore, const float* __restrict__ olr,
    const float* __restrict__ olt, float* __restrict__ out) {
  __shared__ float slr[BV], slt[BV];
  int k = threadIdx.x;  // bv index 0..127
  float s[16], mx = -1e30f;
#pragma unroll
  for (int r = 0; r < 16; ++r) {
    s[r] = oscore[k * 16 + r];
    mx = fmaxf(mx, s[r]);
  }
  float den = 0.0f, wl = 0.0f, wt = 0.0f;
#pragma unroll
  for (int r = 0; r < 16; ++r) {
    float e = __expf((s[r] - mx) * 0.1f);  // /TEMP
    den += e;
    wl += e * olr[k * 16 + r];
    wt += e * olt[k * 16 + r];
  }
  float di = 1.0f / den;
  slr[k] = wl * di;
  slt[k] = wt * di;
  __syncthreads();
  if (k < 8) {
    float a = 0.0f, c = 0.0f;
#pragma unroll
    for (int i = 0; i < 16; ++i) {
      a += slr[k * 16 + i];
      c += slt[k * 16 + i];
    }
    out[k]     = a * (1.0f / 16.0f);  // losses_rot,   (2,B,1) flat
    out[8 + k] = c * (1.0f / 16.0f);  // losses_trans
  }
}

}  // namespace mp

extern "C" void kernel_launch(void* const* d_in, const int* in_sizes, int n_in,
                              void* d_out, int out_size, void* d_ws, size_t ws_size,
                              hipStream_t stream) {
  // input order per setup_inputs(): 0 matches (unused), 1 kps0, 2 kps1,
  // 3 depth0, 4 depth1, 5 T_0to1, 6 K_color0, 7 K_color1, 8/9 Kori (unused),
  // 10 sampled_idx, 11 sampled_idx_ransac
  const float* kps0   = (const float*)d_in[1];
  const float* kps1   = (const float*)d_in[2];
  const float* depth0 = (const float*)d_in[3];
  const float* depth1 = (const float*)d_in[4];
  const float* T01    = (const float*)d_in[5];
  const float* K0     = (const float*)d_in[6];
  const float* K1     = (const float*)d_in[7];
  const int* sidx     = (const int*)d_in[10];
  const int* srans    = (const int*)d_in[11];

  // ws layout: oscore f32[2048] | olr f32[2048] | olt f32[2048]
  float* ws      = (float*)d_ws;
  float* oscore  = ws;
  float* olr     = ws + mp::BIV;
  float* olt     = ws + 2 * mp::BIV;

  mp::pose_fit_kernel<<<mp::BIV, 64, 0, stream>>>(
      kps0, kps1, depth0, depth1, T01, K0, K1, sidx, srans, oscore, olr, olt);
  mp::pose_reduce_kernel<<<1, 128, 0, stream>>>(
      oscore, olr, olt, (float*)d_out);
}

// Round 11
// 14.345 us; speedup vs baseline: 1.0845x; 1.0845x over previous
//
#include <hip/hip_runtime.h>
#include <hip/hip_bf16.h>
#include <math.h>

#ifndef M_PI
#define M_PI 3.14159265358979323846
#endif

namespace mp {

constexpr int NK   = 1024;
constexpr int S    = 256;
constexpr int NREF = 4;
constexpr int BV   = 128;   // B * IT_M
constexpr int BIV  = 2048;  // BV * IT_R
constexpr int NBLK = BIV / 2;  // 1024 blocks, 2 candidates each

// ---- 32-lane-group all-reduce sum (masks 1..16 stay within a half-wave) ----
template <typename T>
__device__ inline T gsum(T v) {
#pragma unroll
  for (int mk = 16; mk >= 1; mk >>= 1) v += __shfl_xor(v, mk, 64);
  return v;
}

// ---- general 3x3 inverse (adjugate / det) in f64 (once per wave),
//      delivered as f32 for the f32 backproject ----
__device__ inline void inv3f(const float* __restrict__ K, float Kf[9]) {
  double a = K[0], b = K[1], c = K[2];
  double d = K[3], e = K[4], f = K[5];
  double g = K[6], h = K[7], i = K[8];
  double A  =  (e * i - f * h);
  double Bm = -(d * i - f * g);
  double C  =  (d * h - e * g);
  double det = a * A + b * Bm + c * C;
  double inv = 1.0 / det;
  Kf[0] = (float)(A * inv);  Kf[1] = (float)(-(b * i - c * h) * inv);  Kf[2] = (float)( (b * f - c * e) * inv);
  Kf[3] = (float)(Bm * inv); Kf[4] = (float)( (a * i - c * g) * inv);  Kf[5] = (float)(-(a * f - c * d) * inv);
  Kf[6] = (float)(C * inv);  Kf[7] = (float)(-(a * h - b * g) * inv);  Kf[8] = (float)( (a * e - b * d) * inv);
}

__device__ inline float det3f(float a, float b, float c,
                              float d, float e, float f,
                              float g, float h, float i) {
  return a * (e * i - f * h) - b * (d * i - f * g) + c * (d * h - e * g);
}

// ---- QUEST solve from reduced moments acc[16]
//      ([0]=sw, [1..3]=sx, [4..6]=sy, [7+3i+j]=Sxy). Horn/Davenport
//      quaternion, closed form: char poly + Newton-from-above + adjugate
//      eigenvector. Values identical across the consuming lanes ->
//      branches uniform; SIMT-shared across a wave's 2 groups. ----
__device__ inline void quest_from_acc(const float acc[16], float R[9], float t[3]) {
  float sw = acc[0];
  float rinv = __fdividef(1.0f, sw + 1e-8f);  // reference's +1e-8 epsilon
  float cx[3], cy[3];
#pragma unroll
  for (int i = 0; i < 3; ++i) { cx[i] = acc[1 + i] * rinv; cy[i] = acc[4 + i] * rinv; }
  float H[3][3];
#pragma unroll
  for (int i = 0; i < 3; ++i)
#pragma unroll
    for (int j = 0; j < 3; ++j)
      H[i][j] = acc[7 + 3 * i + j] - cx[i] * acc[4 + j] - acc[1 + i] * cy[j] +
                sw * cx[i] * cy[j];

  float k00 =  H[0][0] + H[1][1] + H[2][2];
  float k11 =  H[0][0] - H[1][1] - H[2][2];
  float k22 = -H[0][0] + H[1][1] - H[2][2];
  float k33 = -H[0][0] - H[1][1] + H[2][2];
  float k01 = H[1][2] - H[2][1];
  float k02 = H[2][0] - H[0][2];
  float k03 = H[0][1] - H[1][0];
  float k12 = H[0][1] + H[1][0];
  float k13 = H[0][2] + H[2][0];
  float k23 = H[1][2] + H[2][1];

  // char poly p(l) = l^4 + e2 l^2 - e3 l + e4 (trace = 0)
  float e2 = (k00 * k11 - k01 * k01) + (k00 * k22 - k02 * k02) +
             (k00 * k33 - k03 * k03) + (k11 * k22 - k12 * k12) +
             (k11 * k33 - k13 * k13) + (k22 * k33 - k23 * k23);
  float e3 = det3f(k00, k01, k02, k01, k11, k12, k02, k12, k22) +
             det3f(k00, k01, k03, k01, k11, k13, k03, k13, k33) +
             det3f(k00, k02, k03, k02, k22, k23, k03, k23, k33) +
             det3f(k11, k12, k13, k12, k22, k23, k13, k23, k33);
  float M00 = det3f(k11, k12, k13, k12, k22, k23, k13, k23, k33);
  float M01 = det3f(k01, k12, k13, k02, k22, k23, k03, k23, k33);
  float M02 = det3f(k01, k11, k13, k02, k12, k23, k03, k13, k33);
  float M03 = det3f(k01, k11, k12, k02, k12, k22, k03, k13, k23);
  float e4 = k00 * M00 - k01 * M01 + k02 * M02 - k03 * M03;

  // upper bound: min(Gershgorin, Frobenius)*safety; ||K||F^2 = -2 e2
  float g0 = k00 + fabsf(k01) + fabsf(k02) + fabsf(k03);
  float g1 = k11 + fabsf(k01) + fabsf(k12) + fabsf(k13);
  float g2 = k22 + fabsf(k02) + fabsf(k12) + fabsf(k23);
  float g3 = k33 + fabsf(k03) + fabsf(k13) + fabsf(k23);
  float gersh = fmaxf(fmaxf(g0, g1), fmaxf(g2, g3));
  float frob = sqrtf(fmaxf(-2.0f * e2, 0.0f));
  float lam = fmaxf(fminf(gersh, frob), 0.0f) * 1.00001f;

  // Newton from above. Degenerate K~0: 0/0 -> NaN -> n2 guard (R = I).
#pragma unroll
  for (int i = 0; i < 9; ++i) {
    float l2 = lam * lam;
    float p  = ((l2 + e2) * lam - e3) * lam + e4;
    float pp = (4.0f * l2 + 2.0f * e2) * lam - e3;
    lam -= __fdividef(p, pp);
  }

  // eigenvector = max-|diagonal| column of adj(K - lam*I) (= kappa*q*q^T)
  float m00 = k00 - lam, m11 = k11 - lam, m22 = k22 - lam, m33 = k33 - lam;
  float c00 = det3f(m11, k12, k13, k12, m22, k23, k13, k23, m33);
  float c01 = -det3f(k01, k12, k13, k02, m22, k23, k03, k23, m33);
  float c02 = det3f(k01, m11, k13, k02, k12, k23, k03, k13, m33);
  float c03 = -det3f(k01, m11, k12, k02, k12, m22, k03, k13, k23);
  float c11 = det3f(m00, k02, k03, k02, m22, k23, k03, k23, m33);
  float c12 = -det3f(m00, k01, k03, k02, k12, k23, k03, k13, m33);
  float c13 = det3f(m00, k01, k02, k02, k12, m22, k03, k13, k23);
  float c22 = det3f(m00, k01, k03, k01, m11, k13, k03, k13, m33);
  float c23 = -det3f(m00, k01, k02, k01, m11, k12, k03, k13, k23);
  float c33 = det3f(m00, k01, k02, k01, m11, k12, k02, k12, m22);

  float a0 = fabsf(c00), a1 = fabsf(c11), a2 = fabsf(c22), a3 = fabsf(c33);
  float q0 = c00, q1 = c01, q2 = c02, q3 = c03, bb = a0;
  bool t1 = a1 > bb; bb = t1 ? a1 : bb;
  q0 = t1 ? c01 : q0; q1 = t1 ? c11 : q1; q2 = t1 ? c12 : q2; q3 = t1 ? c13 : q3;
  bool t2 = a2 > bb; bb = t2 ? a2 : bb;
  q0 = t2 ? c02 : q0; q1 = t2 ? c12 : q1; q2 = t2 ? c22 : q2; q3 = t2 ? c23 : q3;
  bool t3 = a3 > bb;
  q0 = t3 ? c03 : q0; q1 = t3 ? c13 : q1; q2 = t3 ? c23 : q2; q3 = t3 ? c33 : q3;

  float n2 = q0 * q0 + q1 * q1 + q2 * q2 + q3 * q3;
  bool ok = n2 > 1e-30f;  // degenerate -> R = I (matches SVD(0) behavior)
  float qn = rsqrtf(ok ? n2 : 1.0f);
  float qw = ok ? q0 * qn : 1.0f;
  float qx = ok ? q1 * qn : 0.0f;
  float qy = ok ? q2 * qn : 0.0f;
  float qz = ok ? q3 * qn : 0.0f;

  R[0] = 1.0f - 2.0f * (qy * qy + qz * qz);
  R[1] = 2.0f * (qx * qy - qw * qz);
  R[2] = 2.0f * (qx * qz + qw * qy);
  R[3] = 2.0f * (qx * qy + qw * qz);
  R[4] = 1.0f - 2.0f * (qx * qx + qz * qz);
  R[5] = 2.0f * (qy * qz - qw * qx);
  R[6] = 2.0f * (qx * qz - qw * qy);
  R[7] = 2.0f * (qy * qz + qw * qx);
  R[8] = 1.0f - 2.0f * (qx * qx + qy * qy);
#pragma unroll
  for (int i = 0; i < 3; ++i)
    t[i] = cy[i] - (R[3 * i] * cx[0] + R[3 * i + 1] * cx[1] + R[3 * i + 2] * cx[2]);
}

// ---- masked 256-point Procrustes (8 pts/lane, 8-bit mask) — RARE path,
//      only for refinement iterations >= 1. Moments + 5-level butterfly,
//      then QUEST. ----
__device__ inline void fitq_masked(const float X[8][3], const float Y[8][3],
                                   unsigned wm, float R[9], float t[3]) {
  float acc[16];
  acc[0] = (float)__popc(wm);
#pragma unroll
  for (int r = 1; r < 16; ++r) acc[r] = 0.0f;
#pragma unroll
  for (int k = 0; k < 8; ++k) {
    bool w = (wm >> k) & 1u;
    float x0 = w ? X[k][0] : 0.0f, x1 = w ? X[k][1] : 0.0f, x2 = w ? X[k][2] : 0.0f;
    float y0 = Y[k][0], y1 = Y[k][1], y2 = Y[k][2];
    acc[1] += x0; acc[2] += x1; acc[3] += x2;
    acc[4] += w ? y0 : 0.0f; acc[5] += w ? y1 : 0.0f; acc[6] += w ? y2 : 0.0f;
    acc[7]  += x0 * y0; acc[8]  += x0 * y1; acc[9]  += x0 * y2;
    acc[10] += x1 * y0; acc[11] += x1 * y1; acc[12] += x1 * y2;
    acc[13] += x2 * y0; acc[14] += x2 * y1; acc[15] += x2 * y2;
  }
#pragma unroll
  for (int mk = 16; mk >= 1; mk >>= 1)
#pragma unroll
    for (int r = 0; r < 16; ++r) acc[r] += __shfl_xor(acc[r], mk, 64);
  quest_from_acc(acc, R, t);
}

// ---- fit kernel: 1024 blocks x 64 threads; 2 candidates/wave (32-lane
// groups, 8 points/lane), fully f32.
// Common-path optimization (r10 post-mortem): iteration 0's fit depends on
// only the 5 seed points -> load them directly (group-uniform addresses,
// L1 broadcast), dedup with set-semantics (reference inl0 .at[].set(1.0):
// duplicate seeds count once), accumulate the 16 moments redundantly
// in-registers (no butterfly, no masked 256-pt pass), QUEST as usual.
// The masked+butterfly machinery runs only in the rare improved-loop.
// Exactness model (passed absmax 0.0 in r9):
//  * final procrustes re-fits weights already fit in the loop -> saving the
//    fit at (it==0 || improved) reproduces it.
//  * early-exit when no group improved is a fixed point of the loop.
//  * 'improved' = integer popcount vs pre=NC=5; random clouds give
//    refsum ~ 0 << 5 -> boundary-flip probability << 1e-6. ----
__global__ __launch_bounds__(64) void pose_fit_kernel(
    const float* __restrict__ kps0, const float* __restrict__ kps1,
    const float* __restrict__ depth0, const float* __restrict__ depth1,
    const float* __restrict__ T01,
    const float* __restrict__ K0, const float* __restrict__ K1,
    const int* __restrict__ sidx, const int* __restrict__ sransac,
    float* __restrict__ oscore, float* __restrict__ olr,
    float* __restrict__ olt) {
  const int blk  = blockIdx.x;     // 0..1023
  const int lane = threadIdx.x;    // 0..63
  const int grp  = lane >> 5;      // 0,1
  const int gl   = lane & 31;      // lane in group
  const int m = blk * 2 + grp;     // candidate (0..2047)
  const int v = m >> 4;            // sample row (same for both groups)
  const int b = v >> 4;            // batch

  float Kf0[9], Kf1[9];
  inv3f(K0 + b * 9, Kf0);
  inv3f(K1 + b * 9, Kf1);

  // seed indices (group-uniform) + set-semantics dedup weights
  int r5[5];
#pragma unroll
  for (int c = 0; c < 5; ++c) r5[c] = sransac[m * 5 + c];
  float w5[5];
#pragma unroll
  for (int c = 0; c < 5; ++c) {
    bool dup = false;
#pragma unroll
    for (int j = 0; j < c; ++j) dup = dup || (r5[j] == r5[c]);
    w5[c] = dup ? 0.0f : 1.0f;
  }

  // seed-point moments, accumulated redundantly on every lane (~100 fma;
  // addresses group-uniform -> L1 broadcast loads)
  float accs[16];
#pragma unroll
  for (int r = 0; r < 16; ++r) accs[r] = 0.0f;
#pragma unroll
  for (int c = 0; c < 5; ++c) {
    int idx = sidx[v * S + r5[c]];
    int i0 = idx >> 10;
    int i1 = idx & (NK - 1);
    float u0 = kps0[b * 2 * NK + i0];
    float w0 = kps0[b * 2 * NK + NK + i0];
    float d0 = depth0[b * NK + i0];
    float u1 = kps1[b * 2 * NK + i1];
    float w1 = kps1[b * 2 * NK + NK + i1];
    float d1 = depth1[b * NK + i1];
    float Xc[3], Yc[3];
#pragma unroll
    for (int i = 0; i < 3; ++i) {
      Xc[i] = d0 * (Kf0[3 * i] * u0 + Kf0[3 * i + 1] * w0 + Kf0[3 * i + 2]);
      Yc[i] = d1 * (Kf1[3 * i] * u1 + Kf1[3 * i + 1] * w1 + Kf1[3 * i + 2]);
    }
    float g = w5[c];
    accs[0] += g;
#pragma unroll
    for (int i = 0; i < 3; ++i) {
      float gx = g * Xc[i];
      accs[1 + i] += gx;
      accs[4 + i] += g * Yc[i];
#pragma unroll
      for (int j = 0; j < 3; ++j) accs[7 + 3 * i + j] += gx * Yc[j];
    }
  }

  // gather + backproject 8 points per lane (f32); both groups same data
  float X[8][3], Y[8][3];
#pragma unroll
  for (int k = 0; k < 8; ++k) {
    int s = gl + 32 * k;
    int idx = sidx[v * S + s];
    int i0 = idx >> 10;       // idx / NK
    int i1 = idx & (NK - 1);  // idx % NK
    float u0 = kps0[b * 2 * NK + i0];
    float w0 = kps0[b * 2 * NK + NK + i0];
    float d0 = depth0[b * NK + i0];
    float u1 = kps1[b * 2 * NK + i1];
    float w1 = kps1[b * 2 * NK + NK + i1];
    float d1 = depth1[b * NK + i1];
#pragma unroll
    for (int i = 0; i < 3; ++i) {
      X[k][i] = d0 * (Kf0[3 * i] * u0 + Kf0[3 * i + 1] * w0 + Kf0[3 * i + 2]);
      Y[k][i] = d1 * (Kf1[3 * i] * u1 + Kf1[3 * i + 1] * w1 + Kf1[3 * i + 2]);
    }
  }

  // seed bitmask (bit k <=> point s = gl + 32k) for the rare loop path
  unsigned wm = 0;
#pragma unroll
  for (int c = 0; c < 5; ++c) {
    int r = r5[c];
    if ((r & 31) == gl) wm |= 1u << (r >> 5);
  }

  // ---- iteration 0: QUEST on seed moments, residuals over all points ----
  float R[9], t[3];
  quest_from_acc(accs, R, t);
  unsigned nwm = 0;
  float Rs[9], ts[3], sqs[8];
#pragma unroll
  for (int k = 0; k < 8; ++k) {
    float e0 = Y[k][0] - (R[0] * X[k][0] + R[1] * X[k][1] + R[2] * X[k][2] + t[0]);
    float e1 = Y[k][1] - (R[3] * X[k][0] + R[4] * X[k][1] + R[5] * X[k][2] + t[1]);
    float e2 = Y[k][2] - (R[6] * X[k][0] + R[7] * X[k][1] + R[8] * X[k][2] + t[2]);
    float sq = e0 * e0 + e1 * e1 + e2 * e2;
    sqs[k] = sq;
    nwm |= (sq < 0.0225f) ? (1u << k) : 0u;  // (r < 0.15)
  }
#pragma unroll
  for (int i = 0; i < 9; ++i) Rs[i] = R[i];
#pragma unroll
  for (int i = 0; i < 3; ++i) ts[i] = t[i];
  int rs = gsum(__popc(nwm));
  bool imp = rs > 5;                 // pre = NC = 5
  int pre = imp ? rs : 5;
  wm = imp ? nwm : wm;

  // ---- rare refinement loop (iterations 1..3), masked 256-pt fits ----
  if (__any(imp)) {
    for (int it = 1; it < NREF; ++it) {
      fitq_masked(X, Y, wm, R, t);
      unsigned nw2 = 0;
      float sq32[8];
#pragma unroll
      for (int k = 0; k < 8; ++k) {
        float e0 = Y[k][0] - (R[0] * X[k][0] + R[1] * X[k][1] + R[2] * X[k][2] + t[0]);
        float e1 = Y[k][1] - (R[3] * X[k][0] + R[4] * X[k][1] + R[5] * X[k][2] + t[1]);
        float e2 = Y[k][2] - (R[6] * X[k][0] + R[7] * X[k][1] + R[8] * X[k][2] + t[2]);
        float sq = e0 * e0 + e1 * e1 + e2 * e2;
        sq32[k] = sq;
        nw2 |= (sq < 0.0225f) ? (1u << k) : 0u;
      }
      int rs2 = gsum(__popc(nw2));
      bool imp2 = rs2 > pre;
#pragma unroll
      for (int i = 0; i < 9; ++i) Rs[i] = imp2 ? R[i] : Rs[i];
#pragma unroll
      for (int i = 0; i < 3; ++i) ts[i] = imp2 ? t[i] : ts[i];
#pragma unroll
      for (int k = 0; k < 8; ++k) sqs[k] = imp2 ? sq32[k] : sqs[k];
      pre = imp2 ? rs2 : pre;
      wm  = imp2 ? nw2 : wm;
      if (!__any(imp2)) break;  // per-group fixed point
    }
  }

  // smooth score from saved residuals
  float sc = 0.0f;
#pragma unroll
  for (int k = 0; k < 8; ++k) {
    float r = sqrtf(sqs[k]);
    float xar = 5.0f * (1.0f - r * (1.0f / 0.15f));  // BETA*(1-r/TH)
    sc += 1.0f / (1.0f + __expf(-xar));
  }
  sc = gsum(sc);

  // pose errors vs ground truth T_0to1[b] (tail identical to r8/r9)
  const float* Tb = T01 + b * 16;
  float tr = 0.0f;
#pragma unroll
  for (int i = 0; i < 3; ++i)
#pragma unroll
    for (int j = 0; j < 3; ++j) tr += Rs[i * 3 + j] * Tb[i * 4 + j];
  double xcl = 0.5 * ((double)tr - 1.0);
  const double lo = -1.0 + 1e-6, hi = 1.0 - 1e-6;
  xcl = xcl < lo ? lo : (xcl > hi ? hi : xcl);
  float rot_err = acosf((float)xcl) * (float)(180.0 / M_PI);
  float te0 = ts[0] - Tb[3];
  float te1 = ts[1] - Tb[7];
  float te2 = ts[2] - Tb[11];
  float terr = sqrtf(te0 * te0 + te1 * te1 + te2 * te2);
  float lr = 45.0f * tanhf(rot_err * (1.0f / 45.0f));  // MAX_ROT
  float lt = tanhf(terr);                              // MAX_TRANS = 1

  if (gl == 0) {  // lanes 0 and 32 write their group's candidate
    oscore[m] = sc;
    olr[m] = lr;
    olt[m] = lt;
  }
}

// ---- softmax(score/TEMP) over IT_R=16, weighted losses, mean over IT_M=16 ----
// Output is FLOAT32, flat (2, B, 1) = [rot x8, trans x8].
__global__ __launch_bounds__(128) void pose_reduce_kernel(
    const float* __restrict__ oscore, const float* __restrict__ olr,
    const float* __restrict__ olt, float* __restrict__ out) {
  __shared__ float slr[BV], slt[BV];
  int k = threadIdx.x;  // bv index 0..127
  float s[16], mx = -1e30f;
#pragma unroll
  for (int r = 0; r < 16; ++r) {
    s[r] = oscore[k * 16 + r];
    mx = fmaxf(mx, s[r]);
  }
  float den = 0.0f, wl = 0.0f, wt = 0.0f;
#pragma unroll
  for (int r = 0; r < 16; ++r) {
    float e = __expf((s[r] - mx) * 0.1f);  // /TEMP
    den += e;
    wl += e * olr[k * 16 + r];
    wt += e * olt[k * 16 + r];
  }
  float di = 1.0f / den;
  slr[k] = wl * di;
  slt[k] = wt * di;
  __syncthreads();
  if (k < 8) {
    float a = 0.0f, c = 0.0f;
#pragma unroll
    for (int i = 0; i < 16; ++i) {
      a += slr[k * 16 + i];
      c += slt[k * 16 + i];
    }
    out[k]     = a * (1.0f / 16.0f);  // losses_rot,   (2,B,1) flat
    out[8 + k] = c * (1.0f / 16.0f);  // losses_trans
  }
}

}  // namespace mp

extern "C" void kernel_launch(void* const* d_in, const int* in_sizes, int n_in,
                              void* d_out, int out_size, void* d_ws, size_t ws_size,
                              hipStream_t stream) {
  // input order per setup_inputs(): 0 matches (unused), 1 kps0, 2 kps1,
  // 3 depth0, 4 depth1, 5 T_0to1, 6 K_color0, 7 K_color1, 8/9 Kori (unused),
  // 10 sampled_idx, 11 sampled_idx_ransac
  const float* kps0   = (const float*)d_in[1];
  const float* kps1   = (const float*)d_in[2];
  const float* depth0 = (const float*)d_in[3];
  const float* depth1 = (const float*)d_in[4];
  const float* T01    = (const float*)d_in[5];
  const float* K0     = (const float*)d_in[6];
  const float* K1     = (const float*)d_in[7];
  const int* sidx     = (const int*)d_in[10];
  const int* srans    = (const int*)d_in[11];

  // ws layout: oscore f32[2048] | olr f32[2048] | olt f32[2048]
  float* ws      = (float*)d_ws;
  float* oscore  = ws;
  float* olr     = ws + mp::BIV;
  float* olt     = ws + 2 * mp::BIV;

  mp::pose_fit_kernel<<<mp::NBLK, 64, 0, stream>>>(
      kps0, kps1, depth0, depth1, T01, K0, K1, sidx, srans, oscore, olr, olt);
  mp::pose_reduce_kernel<<<1, 128, 0, stream>>>(
      oscore, olr, olt, (float*)d_out);
}